// Round 1
// baseline (394.618 us; speedup 1.0000x reference)
//
#include <hip/hip_runtime.h>
#include <hip/hip_bf16.h>

#define N_ENT 40000
#define NB 64
#define BODY_LEN 3
#define N_REL 48
#define NUM_POS 24
#define THR 1e-20f

// mem layout: entity-major, mem[ent*64 + b]
// CSR slot: uint2 { meta = nbr | (rEff<<16), val = bits(v) }
//   forward slot (in h's list): nbr=t, rEff=r
//   reverse slot (in t's list): nbr=h, rEff=r+NUM_POS

__global__ void k_zero(int* __restrict__ deg, int* __restrict__ fcnt,
                       float* __restrict__ sums) {
    int i = blockIdx.x * 256 + threadIdx.x;
    if (i < N_ENT) deg[i] = 0;
    if (i < 3) fcnt[i] = 0;
    if (i >= 64 && i < 128) sums[i - 64] = 0.0f;
}

__global__ void k_count(const int* __restrict__ eh, const int* __restrict__ et,
                        int* __restrict__ deg, int nE) {
    int i = blockIdx.x * 256 + threadIdx.x;
    if (i < nE) {
        atomicAdd(&deg[eh[i]], 1);
        atomicAdd(&deg[et[i]], 1);
    }
}

// single-block exclusive scan over deg[0..N_ENT) -> offs[0..N_ENT], csrCur copy
__global__ void k_scan(const int* __restrict__ deg, int* __restrict__ offs,
                       int* __restrict__ csrCur) {
    __shared__ int s_part[1024];
    int t = threadIdx.x;
    int base = t * 40;                       // 1024*40 = 40960 >= 40000
    int end = min(N_ENT, base + 40);
    int local = 0;
    for (int i = base; i < end; ++i) local += deg[i];
    s_part[t] = local;
    __syncthreads();
    for (int off = 1; off < 1024; off <<= 1) {
        int add = (t >= off) ? s_part[t - off] : 0;
        __syncthreads();
        s_part[t] += add;
        __syncthreads();
    }
    int run = (t == 0) ? 0 : s_part[t - 1];  // exclusive base
    for (int i = base; i < end; ++i) {
        int d = deg[i];
        offs[i] = run;
        csrCur[i] = run;
        run += d;
    }
    if (t == 1023) offs[N_ENT] = s_part[1023];  // total = 2*nE
}

// fill CSR; kill-check folded in (killed edges stored with v=0)
__global__ void k_scatter(const int* __restrict__ qh, const int* __restrict__ qr,
                          const int* __restrict__ tt, const int* __restrict__ eh,
                          const int* __restrict__ et, const int* __restrict__ er,
                          const float* __restrict__ ev, int* __restrict__ csrCur,
                          uint2* __restrict__ csr, int nE) {
    __shared__ long long s_key[NB];
    int tid = threadIdx.x;
    if (tid < NB)
        s_key[tid] = ((long long)qh[tid] << 32) | ((long long)tt[tid] << 8) | (long long)qr[tid];
    __syncthreads();
    int i = blockIdx.x * 256 + tid;
    if (i < nE) {
        int h = eh[i], t = et[i], r = er[i];
        long long k = ((long long)h << 32) | ((long long)t << 8) | (long long)r;
        bool killed = false;
#pragma unroll
        for (int b = 0; b < NB; ++b) killed |= (s_key[b] == k);
        float v = killed ? 0.0f : ev[i];
        unsigned vb = __float_as_uint(v);
        int sh = atomicAdd(&csrCur[h], 1);
        csr[sh] = make_uint2((unsigned)t | ((unsigned)r << 16), vb);
        int st = atomicAdd(&csrCur[t], 1);
        csr[st] = make_uint2((unsigned)h | ((unsigned)(r + NUM_POS) << 16), vb);
    }
}

// wave-aggregated frontier append of up-to-4 entities known at lanes 0,16,32,48
__device__ __forceinline__ void frontier_append(unsigned long long m, int lane,
                                                int ent, int* fcnt, int* flist) {
    bool flag = ((lane & 15) == 0) && ((m >> lane) & 0xFFFFULL);
    unsigned long long am = __ballot(flag);
    if (am) {
        int leader = __ffsll((long long)am) - 1;
        int basef = 0;
        if (lane == leader) basef = atomicAdd(fcnt, __popcll(am));
        basef = __shfl(basef, leader);
        if (flag) {
            int rank = __popcll(am & ((1ULL << lane) - 1ULL));
            flist[basef + rank] = ent;
        }
    }
}

// step 0 fused: nxt = one_hot(qh) * decay0; appends step-0 frontier (= qh set)
__global__ void k_init_decay(const int* __restrict__ qh, const float* __restrict__ attn,
                             float* __restrict__ nxt, int* __restrict__ fcnt,
                             int* __restrict__ flist) {
    __shared__ float s_d[NB];
    __shared__ int s_q[NB];
    if (threadIdx.x < NB) {
        s_d[threadIdx.x] = attn[threadIdx.x * (BODY_LEN * N_REL) + 0 * N_REL + (N_REL - 1)];
        s_q[threadIdx.x] = qh[threadIdx.x];
    }
    __syncthreads();
    int i4 = blockIdx.x * 256 + threadIdx.x;       // float4 index
    int ent = (i4 * 4) >> 6;
    int b0 = (i4 * 4) & 63;
    float4 w;
    bool nz = false;
    w.x = (s_q[b0 + 0] == ent) ? s_d[b0 + 0] : 0.0f;
    w.y = (s_q[b0 + 1] == ent) ? s_d[b0 + 1] : 0.0f;
    w.z = (s_q[b0 + 2] == ent) ? s_d[b0 + 2] : 0.0f;
    w.w = (s_q[b0 + 3] == ent) ? s_d[b0 + 3] : 0.0f;
    nz = (s_q[b0 + 0] == ent) | (s_q[b0 + 1] == ent) |
         (s_q[b0 + 2] == ent) | (s_q[b0 + 3] == ent);
    ((float4*)nxt)[i4] = w;
    unsigned long long m = __ballot(nz);
    frontier_append(m, threadIdx.x & 63, ent, fcnt, flist);
}

// nxt = old * decay; appends frontier of entities with any nonzero lane in old
__global__ void k_decay(const float* __restrict__ oldm, float* __restrict__ nxt,
                        const float* __restrict__ attn, int step,
                        int* __restrict__ fcnt, int* __restrict__ flist) {
    __shared__ float s_d[NB];
    if (threadIdx.x < NB)
        s_d[threadIdx.x] = attn[threadIdx.x * (BODY_LEN * N_REL) + step * N_REL + (N_REL - 1)];
    __syncthreads();
    int i4 = blockIdx.x * 256 + threadIdx.x;       // float4 index
    float4 v = ((const float4*)oldm)[i4];
    int b0 = (threadIdx.x * 4) & 63;
    float4 w;
    w.x = v.x * s_d[b0 + 0];
    w.y = v.y * s_d[b0 + 1];
    w.z = v.z * s_d[b0 + 2];
    w.w = v.w * s_d[b0 + 3];
    ((float4*)nxt)[i4] = w;
    bool nz = (v.x != 0.0f) | (v.y != 0.0f) | (v.z != 0.0f) | (v.w != 0.0f);
    unsigned long long m = __ballot(nz);
    int ent = (i4 * 4) >> 6;
    frontier_append(m, threadIdx.x & 63, ent, fcnt, flist);
}

// frontier-centric message pass: one wave per active entity (grid-strided).
// Source row loaded once; CSR slots broadcast via shuffle; per-lane predicated atomics.
template <bool STEP0>
__global__ __launch_bounds__(256) void k_fstep(
    const uint2* __restrict__ csr, const int* __restrict__ offs,
    const int* __restrict__ flist, const int* __restrict__ fcnt,
    const float* __restrict__ attn, int step,
    const float* __restrict__ oldm, const int* __restrict__ qh,
    float* __restrict__ nxt) {
    __shared__ float s_attn[NB][N_REL + 1];  // stride 49: conflict-free
    int tid = threadIdx.x;
    for (int idx = tid; idx < NB * N_REL; idx += 256) {
        int b = idx / N_REL, r = idx % N_REL;
        s_attn[b][r] = attn[b * (BODY_LEN * N_REL) + step * N_REL + r];
    }
    __syncthreads();
    int lane = tid & 63;
    int myqh = STEP0 ? qh[lane] : 0;
    int n = *fcnt;
    int w = (blockIdx.x * 256 + tid) >> 6;
    int nW = (gridDim.x * 256) >> 6;
    for (int f = w; f < n; f += nW) {
        int e = flist[f];
        float src = STEP0 ? ((myqh == e) ? 1.0f : 0.0f)
                          : oldm[(size_t)e * 64 + lane];
        int base = offs[e];
        int cnt = offs[e + 1] - base;
        for (int k0 = 0; k0 < cnt; k0 += 64) {
            uint2 slot = make_uint2(0u, 0u);
            if (k0 + lane < cnt) slot = csr[base + k0 + lane];
            int lim = min(64, cnt - k0);
            for (int j = 0; j < lim; ++j) {
                unsigned meta = (unsigned)__shfl((int)slot.x, j);
                float v = __uint_as_float((unsigned)__shfl((int)slot.y, j));
                if (v == 0.0f) continue;  // killed edge (wave-uniform)
                float val = src * v * s_attn[lane][meta >> 16];
                if (val != 0.0f)
                    atomicAdd(&nxt[(size_t)(meta & 0xFFFFu) * 64 + lane], val);
            }
        }
    }
}

__global__ void k_sums(const float* __restrict__ mem, float* __restrict__ sums) {
    __shared__ float s_s[NB];
    if (threadIdx.x < NB) s_s[threadIdx.x] = 0.0f;
    __syncthreads();
    const float4* m4 = (const float4*)mem;
    const int total4 = NB * N_ENT / 4;
    float4 acc = {0.0f, 0.0f, 0.0f, 0.0f};
    for (int i = blockIdx.x * 256 + threadIdx.x; i < total4; i += gridDim.x * 256) {
        float4 v = m4[i];
        acc.x += v.x; acc.y += v.y; acc.z += v.z; acc.w += v.w;
    }
    int b0 = (threadIdx.x * 4) & 63;   // stride is multiple of 16 float4s -> b fixed
    atomicAdd(&s_s[b0 + 0], acc.x);
    atomicAdd(&s_s[b0 + 1], acc.y);
    atomicAdd(&s_s[b0 + 2], acc.z);
    atomicAdd(&s_s[b0 + 3], acc.w);
    __syncthreads();
    if (threadIdx.x < NB) atomicAdd(&sums[threadIdx.x], s_s[threadIdx.x]);
}

// transpose (ent-major -> batch-major) + normalize; block N_ENT/64 computes the loss
__global__ void k_norm_tr(const float* __restrict__ mem, const float* __restrict__ sums,
                          const int* __restrict__ tt, float* __restrict__ out) {
    if (blockIdx.x == N_ENT / 64) {  // loss block
        int b = threadIdx.x;
        if (b < 64) {
            float p = mem[(size_t)tt[b] * 64 + b] / fmaxf(THR, sums[b]);
            float l = -logf(fmaxf(THR, p));
#pragma unroll
            for (int off = 32; off > 0; off >>= 1) l += __shfl_down(l, off);
            if (b == 0) out[0] = l * (1.0f / 64.0f);
        }
        return;
    }
    __shared__ float tile[64][65];
    __shared__ float s_inv[64];
    int tid = threadIdx.x;
    int e0 = blockIdx.x * 64;
    if (tid < 64) s_inv[tid] = 1.0f / fmaxf(THR, sums[tid]);
    const float4* m4 = (const float4*)(mem + (size_t)e0 * 64);
#pragma unroll
    for (int k = 0; k < 4; ++k) {
        int i4 = k * 256 + tid;         // 1024 float4 = 4096 floats
        float4 v = m4[i4];
        int el = i4 >> 4, b0 = (i4 * 4) & 63;
        tile[el][b0 + 0] = v.x; tile[el][b0 + 1] = v.y;
        tile[el][b0 + 2] = v.z; tile[el][b0 + 3] = v.w;
    }
    __syncthreads();
#pragma unroll
    for (int k = 0; k < 16; ++k) {
        int idx = k * 256 + tid;
        int el = idx & 63, b = idx >> 6;
        out[1 + (size_t)b * N_ENT + e0 + el] = tile[el][b] * s_inv[b];
    }
}

extern "C" void kernel_launch(void* const* d_in, const int* in_sizes, int n_in,
                              void* d_out, int out_size, void* d_ws, size_t ws_size,
                              hipStream_t stream) {
    const int*   qh   = (const int*)d_in[0];
    const int*   qr   = (const int*)d_in[1];
    const int*   tt   = (const int*)d_in[2];
    const float* attn = (const float*)d_in[3];
    const int*   eh   = (const int*)d_in[4];
    const int*   et   = (const int*)d_in[5];
    const int*   er   = (const int*)d_in[6];
    const float* ev   = (const float*)d_in[7];
    float* out = (float*)d_out;
    int nE = in_sizes[4];

    const size_t MEM_BYTES = (size_t)NB * N_ENT * sizeof(float);  // 10,240,000
    char* ws = (char*)d_ws;
    int*   offs   = (int*)ws;                       // (N_ENT+1)*4 = 160 KB
    int*   deg    = (int*)(ws + (192u << 10));      // 160 KB
    int*   csrCur = (int*)(ws + (384u << 10));      // 160 KB
    int*   flist  = (int*)(ws + (576u << 10));      // 160 KB
    int*   fcnt   = (int*)(ws + (768u << 10));      // 12 B
    float* sums   = (float*)(ws + (768u << 10) + 256);  // 256 B
    float* memA   = (float*)(ws + (1u << 20));      // 10.24 MB (always ws)
    float* memB;
    char*  csrBase;
    size_t csrBytes = (size_t)2 * nE * sizeof(uint2);
    size_t needBoth = (size_t)(1u << 20) + 2 * MEM_BYTES + csrBytes;
    if (ws_size >= needBoth) {
        memB = (float*)(ws + (1u << 20) + MEM_BYTES);
        csrBase = ws + (1u << 20) + 2 * MEM_BYTES;
    } else {
        memB = out + 1;  // fallback scratch; k_norm_tr overwrites it at the end
        csrBase = ws + (1u << 20) + MEM_BYTES;
    }
    uint2* csr = (uint2*)csrBase;

    const int NE_F4 = NB * N_ENT / 4 / 256;  // 2500 blocks
    const int EB = (nE + 255) / 256;

    // ---- CSR build (per call; workspace is re-poisoned between iterations) ----
    k_zero<<<(N_ENT + 255) / 256, 256, 0, stream>>>(deg, fcnt, sums);
    k_count<<<EB, 256, 0, stream>>>(eh, et, deg, nE);
    k_scan<<<1, 1024, 0, stream>>>(deg, offs, csrCur);
    k_scatter<<<EB, 256, 0, stream>>>(qh, qr, tt, eh, et, er, ev, csrCur, csr, nE);

    // ---- step 0: virtual one-hot source; nxt = memA ----
    k_init_decay<<<NE_F4, 256, 0, stream>>>(qh, attn, memA, fcnt + 0, flist);
    k_fstep<true><<<16, 256, 0, stream>>>(csr, offs, flist, fcnt + 0, attn, 0,
                                          nullptr, qh, memA);
    // ---- steps 1,2: ping-pong memA <-> memB; final lands in memA ----
    float* curm = memA;
    float* nxtm = memB;
    for (int s = 1; s < BODY_LEN; ++s) {
        k_decay<<<NE_F4, 256, 0, stream>>>(curm, nxtm, attn, s, fcnt + s, flist);
        k_fstep<false><<<1024, 256, 0, stream>>>(csr, offs, flist, fcnt + s, attn, s,
                                                 curm, nullptr, nxtm);
        float* tmp = curm; curm = nxtm; nxtm = tmp;
    }
    // curm == memA (final, ent-major, unnormalized)

    k_sums<<<128, 256, 0, stream>>>(curm, sums);
    k_norm_tr<<<N_ENT / 64 + 1, 256, 0, stream>>>(curm, sums, tt, out);
}

// Round 2
// 303.808 us; speedup vs baseline: 1.2989x; 1.2989x over previous
//
#include <hip/hip_runtime.h>
#include <hip/hip_bf16.h>

#define N_ENT 40000
#define NB 64
#define BODY_LEN 3
#define N_REL 48
#define NUM_POS 24
#define THR 1e-20f

// mem layout: entity-major, mem[ent*64 + b]
// CSR slot: uint2 { meta = nbr | (rEff<<16), val = bits(v) }
//   forward slot (in h's list): nbr=t, rEff=r
//   reverse slot (in t's list): nbr=h, rEff=r+NUM_POS

__global__ void k_zero(int* __restrict__ deg, int* __restrict__ fcnt,
                       float* __restrict__ sums) {
    int i = blockIdx.x * 256 + threadIdx.x;
    if (i < N_ENT) deg[i] = 0;
    if (i < 3) fcnt[i] = 0;
    if (i >= 64 && i < 128) sums[i - 64] = 0.0f;
}

__global__ void k_count(const int* __restrict__ eh, const int* __restrict__ et,
                        int* __restrict__ deg, int nE) {
    int i = blockIdx.x * 256 + threadIdx.x;
    if (i < nE) {
        atomicAdd(&deg[eh[i]], 1);
        atomicAdd(&deg[et[i]], 1);
    }
}

// single-block exclusive scan over deg[0..N_ENT) -> offs[0..N_ENT], csrCur copy
__global__ void k_scan(const int* __restrict__ deg, int* __restrict__ offs,
                       int* __restrict__ csrCur) {
    __shared__ int s_part[1024];
    int t = threadIdx.x;
    int base = t * 40;                       // 1024*40 = 40960 >= 40000
    int end = min(N_ENT, base + 40);
    int local = 0;
    for (int i = base; i < end; ++i) local += deg[i];
    s_part[t] = local;
    __syncthreads();
    for (int off = 1; off < 1024; off <<= 1) {
        int add = (t >= off) ? s_part[t - off] : 0;
        __syncthreads();
        s_part[t] += add;
        __syncthreads();
    }
    int run = (t == 0) ? 0 : s_part[t - 1];  // exclusive base
    for (int i = base; i < end; ++i) {
        int d = deg[i];
        offs[i] = run;
        csrCur[i] = run;
        run += d;
    }
    if (t == 1023) offs[N_ENT] = s_part[1023];  // total = 2*nE
}

// fill CSR; kill-check folded in (killed edges stored with v=0)
__global__ void k_scatter(const int* __restrict__ qh, const int* __restrict__ qr,
                          const int* __restrict__ tt, const int* __restrict__ eh,
                          const int* __restrict__ et, const int* __restrict__ er,
                          const float* __restrict__ ev, int* __restrict__ csrCur,
                          uint2* __restrict__ csr, int nE) {
    __shared__ long long s_key[NB];
    int tid = threadIdx.x;
    if (tid < NB)
        s_key[tid] = ((long long)qh[tid] << 32) | ((long long)tt[tid] << 8) | (long long)qr[tid];
    __syncthreads();
    int i = blockIdx.x * 256 + tid;
    if (i < nE) {
        int h = eh[i], t = et[i], r = er[i];
        long long k = ((long long)h << 32) | ((long long)t << 8) | (long long)r;
        bool killed = false;
#pragma unroll
        for (int b = 0; b < NB; ++b) killed |= (s_key[b] == k);
        float v = killed ? 0.0f : ev[i];
        unsigned vb = __float_as_uint(v);
        int sh = atomicAdd(&csrCur[h], 1);
        csr[sh] = make_uint2((unsigned)t | ((unsigned)r << 16), vb);
        int st = atomicAdd(&csrCur[t], 1);
        csr[st] = make_uint2((unsigned)h | ((unsigned)(r + NUM_POS) << 16), vb);
    }
}

// ---- frontier aggregation helpers (block-local; ONE global atomic per block) ----
// Each wave iteration covers 16 entities (lanes 0,16,32,48 own 4-entity groups).
// Entities flagged into an LDS list; flushed once at block end.

#define DEC_BLOCKS 320
#define FLIST_LDS 192   // max 8 grid-stride iters * 16 entities = 128; padded

__device__ __forceinline__ void flag_entities(unsigned long long m, int lane,
                                              int ent, int* s_cnt, int* s_list) {
    bool flag = ((lane & 15) == 0) && ((m >> lane) & 0xFFFFULL);
    unsigned long long am = __ballot(flag);
    if (am) {
        int leader = __ffsll((long long)am) - 1;
        int lb = 0;
        if (lane == leader) lb = atomicAdd(s_cnt, __popcll(am));
        lb = __shfl(lb, leader);
        if (flag) {
            int rank = __popcll(am & ((1ULL << lane) - 1ULL));
            s_list[lb + rank] = ent;
        }
    }
}

// step 0 fused: nxt = one_hot(qh) * decay0; appends step-0 frontier (= qh set)
__global__ void k_init_decay(const int* __restrict__ qh, const float* __restrict__ attn,
                             float* __restrict__ nxt, int* __restrict__ fcnt,
                             int* __restrict__ flist) {
    __shared__ float s_d[NB];
    __shared__ int s_q[NB];
    __shared__ int s_list[FLIST_LDS];
    __shared__ int s_cnt, s_gbase;
    int tid = threadIdx.x;
    if (tid < NB) {
        s_d[tid] = attn[tid * (BODY_LEN * N_REL) + 0 * N_REL + (N_REL - 1)];
        s_q[tid] = qh[tid];
    }
    if (tid == 0) s_cnt = 0;
    __syncthreads();
    int lane = tid & 63;
    const int total4 = NB * N_ENT / 4;       // 640000, divisible by 256
    for (int i4 = blockIdx.x * 256 + tid; i4 < total4; i4 += gridDim.x * 256) {
        int ent = (i4 * 4) >> 6;
        int b0 = (i4 * 4) & 63;
        float4 w;
        w.x = (s_q[b0 + 0] == ent) ? s_d[b0 + 0] : 0.0f;
        w.y = (s_q[b0 + 1] == ent) ? s_d[b0 + 1] : 0.0f;
        w.z = (s_q[b0 + 2] == ent) ? s_d[b0 + 2] : 0.0f;
        w.w = (s_q[b0 + 3] == ent) ? s_d[b0 + 3] : 0.0f;
        ((float4*)nxt)[i4] = w;
        bool nz = (s_q[b0 + 0] == ent) | (s_q[b0 + 1] == ent) |
                  (s_q[b0 + 2] == ent) | (s_q[b0 + 3] == ent);
        unsigned long long m = __ballot(nz);
        flag_entities(m, lane, ent, &s_cnt, s_list);
    }
    __syncthreads();
    if (tid == 0 && s_cnt) s_gbase = atomicAdd(fcnt, s_cnt);
    __syncthreads();
    for (int i = tid; i < s_cnt; i += 256) flist[s_gbase + i] = s_list[i];
}

// nxt = old * decay; appends frontier of entities with any nonzero lane in old
__global__ void k_decay(const float* __restrict__ oldm, float* __restrict__ nxt,
                        const float* __restrict__ attn, int step,
                        int* __restrict__ fcnt, int* __restrict__ flist) {
    __shared__ float s_d[NB];
    __shared__ int s_list[FLIST_LDS];
    __shared__ int s_cnt, s_gbase;
    int tid = threadIdx.x;
    if (tid < NB)
        s_d[tid] = attn[tid * (BODY_LEN * N_REL) + step * N_REL + (N_REL - 1)];
    if (tid == 0) s_cnt = 0;
    __syncthreads();
    int lane = tid & 63;
    const int total4 = NB * N_ENT / 4;       // 640000, divisible by 256
    for (int i4 = blockIdx.x * 256 + tid; i4 < total4; i4 += gridDim.x * 256) {
        float4 v = ((const float4*)oldm)[i4];
        int b0 = (tid * 4) & 63;
        float4 w;
        w.x = v.x * s_d[b0 + 0];
        w.y = v.y * s_d[b0 + 1];
        w.z = v.z * s_d[b0 + 2];
        w.w = v.w * s_d[b0 + 3];
        ((float4*)nxt)[i4] = w;
        bool nz = (v.x != 0.0f) | (v.y != 0.0f) | (v.z != 0.0f) | (v.w != 0.0f);
        unsigned long long m = __ballot(nz);
        flag_entities(m, lane, (i4 * 4) >> 6, &s_cnt, s_list);
    }
    __syncthreads();
    if (tid == 0 && s_cnt) s_gbase = atomicAdd(fcnt, s_cnt);
    __syncthreads();
    for (int i = tid; i < s_cnt; i += 256) flist[s_gbase + i] = s_list[i];
}

// frontier-centric message pass: one wave per active entity (grid-strided).
// Source row loaded once; CSR slots broadcast via shuffle; per-lane predicated atomics.
template <bool STEP0>
__global__ __launch_bounds__(256) void k_fstep(
    const uint2* __restrict__ csr, const int* __restrict__ offs,
    const int* __restrict__ flist, const int* __restrict__ fcnt,
    const float* __restrict__ attn, int step,
    const float* __restrict__ oldm, const int* __restrict__ qh,
    float* __restrict__ nxt) {
    __shared__ float s_attn[NB][N_REL + 1];  // stride 49: conflict-free
    int tid = threadIdx.x;
    for (int idx = tid; idx < NB * N_REL; idx += 256) {
        int b = idx / N_REL, r = idx % N_REL;
        s_attn[b][r] = attn[b * (BODY_LEN * N_REL) + step * N_REL + r];
    }
    __syncthreads();
    int lane = tid & 63;
    int myqh = STEP0 ? qh[lane] : 0;
    int n = *fcnt;
    int w = (blockIdx.x * 256 + tid) >> 6;
    int nW = (gridDim.x * 256) >> 6;
    for (int f = w; f < n; f += nW) {
        int e = flist[f];
        float src = STEP0 ? ((myqh == e) ? 1.0f : 0.0f)
                          : oldm[(size_t)e * 64 + lane];
        int base = offs[e];
        int cnt = offs[e + 1] - base;
        for (int k0 = 0; k0 < cnt; k0 += 64) {
            uint2 slot = make_uint2(0u, 0u);
            if (k0 + lane < cnt) slot = csr[base + k0 + lane];
            int lim = min(64, cnt - k0);
            for (int j = 0; j < lim; ++j) {
                unsigned meta = (unsigned)__shfl((int)slot.x, j);
                float v = __uint_as_float((unsigned)__shfl((int)slot.y, j));
                if (v == 0.0f) continue;  // killed edge (wave-uniform)
                float val = src * v * s_attn[lane][meta >> 16];
                if (val != 0.0f)
                    atomicAdd(&nxt[(size_t)(meta & 0xFFFFu) * 64 + lane], val);
            }
        }
    }
}

__global__ void k_sums(const float* __restrict__ mem, float* __restrict__ sums) {
    __shared__ float s_s[NB];
    if (threadIdx.x < NB) s_s[threadIdx.x] = 0.0f;
    __syncthreads();
    const float4* m4 = (const float4*)mem;
    const int total4 = NB * N_ENT / 4;
    float4 acc = {0.0f, 0.0f, 0.0f, 0.0f};
    for (int i = blockIdx.x * 256 + threadIdx.x; i < total4; i += gridDim.x * 256) {
        float4 v = m4[i];
        acc.x += v.x; acc.y += v.y; acc.z += v.z; acc.w += v.w;
    }
    int b0 = (threadIdx.x * 4) & 63;   // stride is multiple of 16 float4s -> b fixed
    atomicAdd(&s_s[b0 + 0], acc.x);
    atomicAdd(&s_s[b0 + 1], acc.y);
    atomicAdd(&s_s[b0 + 2], acc.z);
    atomicAdd(&s_s[b0 + 3], acc.w);
    __syncthreads();
    if (threadIdx.x < NB) atomicAdd(&sums[threadIdx.x], s_s[threadIdx.x]);
}

// transpose (ent-major -> batch-major) + normalize; block N_ENT/64 computes the loss
__global__ void k_norm_tr(const float* __restrict__ mem, const float* __restrict__ sums,
                          const int* __restrict__ tt, float* __restrict__ out) {
    if (blockIdx.x == N_ENT / 64) {  // loss block
        int b = threadIdx.x;
        if (b < 64) {
            float p = mem[(size_t)tt[b] * 64 + b] / fmaxf(THR, sums[b]);
            float l = -logf(fmaxf(THR, p));
#pragma unroll
            for (int off = 32; off > 0; off >>= 1) l += __shfl_down(l, off);
            if (b == 0) out[0] = l * (1.0f / 64.0f);
        }
        return;
    }
    __shared__ float tile[64][65];
    __shared__ float s_inv[64];
    int tid = threadIdx.x;
    int e0 = blockIdx.x * 64;
    if (tid < 64) s_inv[tid] = 1.0f / fmaxf(THR, sums[tid]);
    const float4* m4 = (const float4*)(mem + (size_t)e0 * 64);
#pragma unroll
    for (int k = 0; k < 4; ++k) {
        int i4 = k * 256 + tid;         // 1024 float4 = 4096 floats
        float4 v = m4[i4];
        int el = i4 >> 4, b0 = (i4 * 4) & 63;
        tile[el][b0 + 0] = v.x; tile[el][b0 + 1] = v.y;
        tile[el][b0 + 2] = v.z; tile[el][b0 + 3] = v.w;
    }
    __syncthreads();
#pragma unroll
    for (int k = 0; k < 16; ++k) {
        int idx = k * 256 + tid;
        int el = idx & 63, b = idx >> 6;
        out[1 + (size_t)b * N_ENT + e0 + el] = tile[el][b] * s_inv[b];
    }
}

extern "C" void kernel_launch(void* const* d_in, const int* in_sizes, int n_in,
                              void* d_out, int out_size, void* d_ws, size_t ws_size,
                              hipStream_t stream) {
    const int*   qh   = (const int*)d_in[0];
    const int*   qr   = (const int*)d_in[1];
    const int*   tt   = (const int*)d_in[2];
    const float* attn = (const float*)d_in[3];
    const int*   eh   = (const int*)d_in[4];
    const int*   et   = (const int*)d_in[5];
    const int*   er   = (const int*)d_in[6];
    const float* ev   = (const float*)d_in[7];
    float* out = (float*)d_out;
    int nE = in_sizes[4];

    const size_t MEM_BYTES = (size_t)NB * N_ENT * sizeof(float);  // 10,240,000
    char* ws = (char*)d_ws;
    int*   offs   = (int*)ws;                       // (N_ENT+1)*4 = 160 KB
    int*   deg    = (int*)(ws + (192u << 10));      // 160 KB
    int*   csrCur = (int*)(ws + (384u << 10));      // 160 KB
    int*   flist  = (int*)(ws + (576u << 10));      // 160 KB
    int*   fcnt   = (int*)(ws + (768u << 10));      // 12 B
    float* sums   = (float*)(ws + (768u << 10) + 256);  // 256 B
    float* memA   = (float*)(ws + (1u << 20));      // 10.24 MB (always ws)
    float* memB;
    char*  csrBase;
    size_t csrBytes = (size_t)2 * nE * sizeof(uint2);
    size_t needBoth = (size_t)(1u << 20) + 2 * MEM_BYTES + csrBytes;
    if (ws_size >= needBoth) {
        memB = (float*)(ws + (1u << 20) + MEM_BYTES);
        csrBase = ws + (1u << 20) + 2 * MEM_BYTES;
    } else {
        memB = out + 1;  // fallback scratch; k_norm_tr overwrites it at the end
        csrBase = ws + (1u << 20) + MEM_BYTES;
    }
    uint2* csr = (uint2*)csrBase;

    const int EB = (nE + 255) / 256;

    // ---- CSR build (per call; workspace is re-poisoned between iterations) ----
    k_zero<<<(N_ENT + 255) / 256, 256, 0, stream>>>(deg, fcnt, sums);
    k_count<<<EB, 256, 0, stream>>>(eh, et, deg, nE);
    k_scan<<<1, 1024, 0, stream>>>(deg, offs, csrCur);
    k_scatter<<<EB, 256, 0, stream>>>(qh, qr, tt, eh, et, er, ev, csrCur, csr, nE);

    // ---- step 0: virtual one-hot source; nxt = memA ----
    k_init_decay<<<DEC_BLOCKS, 256, 0, stream>>>(qh, attn, memA, fcnt + 0, flist);
    k_fstep<true><<<16, 256, 0, stream>>>(csr, offs, flist, fcnt + 0, attn, 0,
                                          nullptr, qh, memA);
    // ---- steps 1,2: ping-pong memA <-> memB; final lands in memA ----
    float* curm = memA;
    float* nxtm = memB;
    for (int s = 1; s < BODY_LEN; ++s) {
        k_decay<<<DEC_BLOCKS, 256, 0, stream>>>(curm, nxtm, attn, s, fcnt + s, flist);
        k_fstep<false><<<1024, 256, 0, stream>>>(csr, offs, flist, fcnt + s, attn, s,
                                                 curm, nullptr, nxtm);
        float* tmp = curm; curm = nxtm; nxtm = tmp;
    }
    // curm == memA (final, ent-major, unnormalized)

    k_sums<<<128, 256, 0, stream>>>(curm, sums);
    k_norm_tr<<<N_ENT / 64 + 1, 256, 0, stream>>>(curm, sums, tt, out);
}

// Round 3
// 222.443 us; speedup vs baseline: 1.7740x; 1.3658x over previous
//
#include <hip/hip_runtime.h>
#include <hip/hip_bf16.h>

#define N_ENT 40000
#define NB 64
#define BODY_LEN 3
#define N_REL 48
#define NUM_POS 24
#define THR 1e-20f

#define SCAN_NBLK ((N_ENT + 255) / 256)   // 157

// mem layout: entity-major, mem[ent*64 + b]
// CSR slot: uint2 { meta = nbr | (rEff<<16), val = bits(v) }
//   forward slot (in h's list): nbr=t, rEff=r
//   reverse slot (in t's list): nbr=h, rEff=r+NUM_POS

__global__ void k_zero(int* __restrict__ deg, int* __restrict__ fcnt,
                       float* __restrict__ sums) {
    int i = blockIdx.x * 256 + threadIdx.x;
    if (i < N_ENT) deg[i] = 0;
    if (i < 3) fcnt[i] = 0;
    if (i >= 64 && i < 128) sums[i - 64] = 0.0f;
}

__global__ void k_count(const int* __restrict__ eh, const int* __restrict__ et,
                        int* __restrict__ deg, int nE) {
    int i = blockIdx.x * 256 + threadIdx.x;
    if (i < nE) {
        atomicAdd(&deg[eh[i]], 1);
        atomicAdd(&deg[et[i]], 1);
    }
}

// ---- hierarchical exclusive scan of deg[0..N_ENT) -> offs, csrCur ----
__global__ void k_blocksum(const int* __restrict__ deg, int* __restrict__ partial) {
    __shared__ int ws[4];
    int t = threadIdx.x;
    int i = blockIdx.x * 256 + t;
    int v = (i < N_ENT) ? deg[i] : 0;
#pragma unroll
    for (int off = 32; off > 0; off >>= 1) v += __shfl_down(v, off);
    if ((t & 63) == 0) ws[t >> 6] = v;
    __syncthreads();
    if (t == 0) partial[blockIdx.x] = ws[0] + ws[1] + ws[2] + ws[3];
}

__global__ void k_scan_small(const int* __restrict__ partial, int* __restrict__ pofs,
                             int* __restrict__ offs) {
    __shared__ int s[256];
    int t = threadIdx.x;
    int v = (t < SCAN_NBLK) ? partial[t] : 0;
    s[t] = v;
    __syncthreads();
    for (int off = 1; off < 256; off <<= 1) {
        int add = (t >= off) ? s[t - off] : 0;
        __syncthreads();
        s[t] += add;
        __syncthreads();
    }
    if (t < SCAN_NBLK) pofs[t] = s[t] - v;   // exclusive base for block t
    if (t == 255) offs[N_ENT] = s[255];      // total = 2*nE
}

__global__ void k_offsets(const int* __restrict__ deg, const int* __restrict__ pofs,
                          int* __restrict__ offs, int* __restrict__ csrCur) {
    __shared__ int s[256];
    int t = threadIdx.x;
    int i = blockIdx.x * 256 + t;
    int v = (i < N_ENT) ? deg[i] : 0;
    s[t] = v;
    __syncthreads();
    for (int off = 1; off < 256; off <<= 1) {
        int add = (t >= off) ? s[t - off] : 0;
        __syncthreads();
        s[t] += add;
        __syncthreads();
    }
    if (i < N_ENT) {
        int ex = pofs[blockIdx.x] + s[t] - v;
        offs[i] = ex;
        csrCur[i] = ex;
    }
}

// fill CSR; kill-check folded in (killed edges stored with v=0)
__global__ void k_scatter(const int* __restrict__ qh, const int* __restrict__ qr,
                          const int* __restrict__ tt, const int* __restrict__ eh,
                          const int* __restrict__ et, const int* __restrict__ er,
                          const float* __restrict__ ev, int* __restrict__ csrCur,
                          uint2* __restrict__ csr, int nE) {
    __shared__ long long s_key[NB];
    int tid = threadIdx.x;
    if (tid < NB)
        s_key[tid] = ((long long)qh[tid] << 32) | ((long long)tt[tid] << 8) | (long long)qr[tid];
    __syncthreads();
    int i = blockIdx.x * 256 + tid;
    if (i < nE) {
        int h = eh[i], t = et[i], r = er[i];
        long long k = ((long long)h << 32) | ((long long)t << 8) | (long long)r;
        bool killed = false;
#pragma unroll
        for (int b = 0; b < NB; ++b) killed |= (s_key[b] == k);
        float v = killed ? 0.0f : ev[i];
        unsigned vb = __float_as_uint(v);
        int sh = atomicAdd(&csrCur[h], 1);
        csr[sh] = make_uint2((unsigned)t | ((unsigned)r << 16), vb);
        int st = atomicAdd(&csrCur[t], 1);
        csr[st] = make_uint2((unsigned)h | ((unsigned)(r + NUM_POS) << 16), vb);
    }
}

// ---- frontier aggregation helpers (block-local; ONE global atomic per block) ----
#define DEC_BLOCKS 320
#define FLIST_LDS 192   // max 8 grid-stride iters * 16 entities = 128; padded

__device__ __forceinline__ void flag_entities(unsigned long long m, int lane,
                                              int ent, int* s_cnt, int* s_list) {
    bool flag = ((lane & 15) == 0) && ((m >> lane) & 0xFFFFULL);
    unsigned long long am = __ballot(flag);
    if (am) {
        int leader = __ffsll((long long)am) - 1;
        int lb = 0;
        if (lane == leader) lb = atomicAdd(s_cnt, __popcll(am));
        lb = __shfl(lb, leader);
        if (flag) {
            int rank = __popcll(am & ((1ULL << lane) - 1ULL));
            s_list[lb + rank] = ent;
        }
    }
}

// step 0 fused: nxt = one_hot(qh) * decay0; appends step-0 frontier (= qh set)
__global__ void k_init_decay(const int* __restrict__ qh, const float* __restrict__ attn,
                             float* __restrict__ nxt, int* __restrict__ fcnt,
                             int* __restrict__ flist) {
    __shared__ float s_d[NB];
    __shared__ int s_q[NB];
    __shared__ int s_list[FLIST_LDS];
    __shared__ int s_cnt, s_gbase;
    int tid = threadIdx.x;
    if (tid < NB) {
        s_d[tid] = attn[tid * (BODY_LEN * N_REL) + 0 * N_REL + (N_REL - 1)];
        s_q[tid] = qh[tid];
    }
    if (tid == 0) s_cnt = 0;
    __syncthreads();
    int lane = tid & 63;
    const int total4 = NB * N_ENT / 4;       // 640000, divisible by 256
    for (int i4 = blockIdx.x * 256 + tid; i4 < total4; i4 += gridDim.x * 256) {
        int ent = (i4 * 4) >> 6;
        int b0 = (i4 * 4) & 63;
        float4 w;
        w.x = (s_q[b0 + 0] == ent) ? s_d[b0 + 0] : 0.0f;
        w.y = (s_q[b0 + 1] == ent) ? s_d[b0 + 1] : 0.0f;
        w.z = (s_q[b0 + 2] == ent) ? s_d[b0 + 2] : 0.0f;
        w.w = (s_q[b0 + 3] == ent) ? s_d[b0 + 3] : 0.0f;
        ((float4*)nxt)[i4] = w;
        bool nz = (s_q[b0 + 0] == ent) | (s_q[b0 + 1] == ent) |
                  (s_q[b0 + 2] == ent) | (s_q[b0 + 3] == ent);
        unsigned long long m = __ballot(nz);
        flag_entities(m, lane, ent, &s_cnt, s_list);
    }
    __syncthreads();
    if (tid == 0 && s_cnt) s_gbase = atomicAdd(fcnt, s_cnt);
    __syncthreads();
    for (int i = tid; i < s_cnt; i += 256) flist[s_gbase + i] = s_list[i];
}

// nxt = old * decay; appends frontier of entities with any nonzero lane in old
__global__ void k_decay(const float* __restrict__ oldm, float* __restrict__ nxt,
                        const float* __restrict__ attn, int step,
                        int* __restrict__ fcnt, int* __restrict__ flist) {
    __shared__ float s_d[NB];
    __shared__ int s_list[FLIST_LDS];
    __shared__ int s_cnt, s_gbase;
    int tid = threadIdx.x;
    if (tid < NB)
        s_d[tid] = attn[tid * (BODY_LEN * N_REL) + step * N_REL + (N_REL - 1)];
    if (tid == 0) s_cnt = 0;
    __syncthreads();
    int lane = tid & 63;
    const int total4 = NB * N_ENT / 4;       // 640000, divisible by 256
    for (int i4 = blockIdx.x * 256 + tid; i4 < total4; i4 += gridDim.x * 256) {
        float4 v = ((const float4*)oldm)[i4];
        int b0 = (tid * 4) & 63;
        float4 w;
        w.x = v.x * s_d[b0 + 0];
        w.y = v.y * s_d[b0 + 1];
        w.z = v.z * s_d[b0 + 2];
        w.w = v.w * s_d[b0 + 3];
        ((float4*)nxt)[i4] = w;
        bool nz = (v.x != 0.0f) | (v.y != 0.0f) | (v.z != 0.0f) | (v.w != 0.0f);
        unsigned long long m = __ballot(nz);
        flag_entities(m, lane, (i4 * 4) >> 6, &s_cnt, s_list);
    }
    __syncthreads();
    if (tid == 0 && s_cnt) s_gbase = atomicAdd(fcnt, s_cnt);
    __syncthreads();
    for (int i = tid; i < s_cnt; i += 256) flist[s_gbase + i] = s_list[i];
}

// frontier-centric message pass: one wave per active entity (grid-strided).
template <bool STEP0>
__global__ __launch_bounds__(256) void k_fstep(
    const uint2* __restrict__ csr, const int* __restrict__ offs,
    const int* __restrict__ flist, const int* __restrict__ fcnt,
    const float* __restrict__ attn, int step,
    const float* __restrict__ oldm, const int* __restrict__ qh,
    float* __restrict__ nxt) {
    __shared__ float s_attn[NB][N_REL + 1];  // stride 49: conflict-free
    int tid = threadIdx.x;
    for (int idx = tid; idx < NB * N_REL; idx += 256) {
        int b = idx / N_REL, r = idx % N_REL;
        s_attn[b][r] = attn[b * (BODY_LEN * N_REL) + step * N_REL + r];
    }
    __syncthreads();
    int lane = tid & 63;
    int myqh = STEP0 ? qh[lane] : 0;
    int n = *fcnt;
    int w = (blockIdx.x * 256 + tid) >> 6;
    int nW = (gridDim.x * 256) >> 6;
    for (int f = w; f < n; f += nW) {
        int e = flist[f];
        float src = STEP0 ? ((myqh == e) ? 1.0f : 0.0f)
                          : oldm[(size_t)e * 64 + lane];
        int base = offs[e];
        int cnt = offs[e + 1] - base;
        for (int k0 = 0; k0 < cnt; k0 += 64) {
            uint2 slot = make_uint2(0u, 0u);
            if (k0 + lane < cnt) slot = csr[base + k0 + lane];
            int lim = min(64, cnt - k0);
            for (int j = 0; j < lim; ++j) {
                unsigned meta = (unsigned)__shfl((int)slot.x, j);
                float v = __uint_as_float((unsigned)__shfl((int)slot.y, j));
                if (v == 0.0f) continue;  // killed edge (wave-uniform)
                float val = src * v * s_attn[lane][meta >> 16];
                if (val != 0.0f)
                    atomicAdd(&nxt[(size_t)(meta & 0xFFFFu) * 64 + lane], val);
            }
        }
    }
}

__global__ void k_sums(const float* __restrict__ mem, float* __restrict__ sums) {
    __shared__ float s_s[NB];
    if (threadIdx.x < NB) s_s[threadIdx.x] = 0.0f;
    __syncthreads();
    const float4* m4 = (const float4*)mem;
    const int total4 = NB * N_ENT / 4;
    float4 acc = {0.0f, 0.0f, 0.0f, 0.0f};
    for (int i = blockIdx.x * 256 + threadIdx.x; i < total4; i += gridDim.x * 256) {
        float4 v = m4[i];
        acc.x += v.x; acc.y += v.y; acc.z += v.z; acc.w += v.w;
    }
    int b0 = (threadIdx.x * 4) & 63;   // stride is multiple of 16 float4s -> b fixed
    atomicAdd(&s_s[b0 + 0], acc.x);
    atomicAdd(&s_s[b0 + 1], acc.y);
    atomicAdd(&s_s[b0 + 2], acc.z);
    atomicAdd(&s_s[b0 + 3], acc.w);
    __syncthreads();
    if (threadIdx.x < NB) atomicAdd(&sums[threadIdx.x], s_s[threadIdx.x]);
}

// transpose (ent-major -> batch-major) + normalize; block N_ENT/64 computes the loss
__global__ void k_norm_tr(const float* __restrict__ mem, const float* __restrict__ sums,
                          const int* __restrict__ tt, float* __restrict__ out) {
    if (blockIdx.x == N_ENT / 64) {  // loss block
        int b = threadIdx.x;
        if (b < 64) {
            float p = mem[(size_t)tt[b] * 64 + b] / fmaxf(THR, sums[b]);
            float l = -logf(fmaxf(THR, p));
#pragma unroll
            for (int off = 32; off > 0; off >>= 1) l += __shfl_down(l, off);
            if (b == 0) out[0] = l * (1.0f / 64.0f);
        }
        return;
    }
    __shared__ float tile[64][65];
    __shared__ float s_inv[64];
    int tid = threadIdx.x;
    int e0 = blockIdx.x * 64;
    if (tid < 64) s_inv[tid] = 1.0f / fmaxf(THR, sums[tid]);
    const float4* m4 = (const float4*)(mem + (size_t)e0 * 64);
#pragma unroll
    for (int k = 0; k < 4; ++k) {
        int i4 = k * 256 + tid;         // 1024 float4 = 4096 floats
        float4 v = m4[i4];
        int el = i4 >> 4, b0 = (i4 * 4) & 63;
        tile[el][b0 + 0] = v.x; tile[el][b0 + 1] = v.y;
        tile[el][b0 + 2] = v.z; tile[el][b0 + 3] = v.w;
    }
    __syncthreads();
#pragma unroll
    for (int k = 0; k < 16; ++k) {
        int idx = k * 256 + tid;
        int el = idx & 63, b = idx >> 6;
        out[1 + (size_t)b * N_ENT + e0 + el] = tile[el][b] * s_inv[b];
    }
}

extern "C" void kernel_launch(void* const* d_in, const int* in_sizes, int n_in,
                              void* d_out, int out_size, void* d_ws, size_t ws_size,
                              hipStream_t stream) {
    const int*   qh   = (const int*)d_in[0];
    const int*   qr   = (const int*)d_in[1];
    const int*   tt   = (const int*)d_in[2];
    const float* attn = (const float*)d_in[3];
    const int*   eh   = (const int*)d_in[4];
    const int*   et   = (const int*)d_in[5];
    const int*   er   = (const int*)d_in[6];
    const float* ev   = (const float*)d_in[7];
    float* out = (float*)d_out;
    int nE = in_sizes[4];

    const size_t MEM_BYTES = (size_t)NB * N_ENT * sizeof(float);  // 10,240,000
    char* ws = (char*)d_ws;
    int*   offs    = (int*)ws;                       // (N_ENT+1)*4 = 160 KB
    int*   deg     = (int*)(ws + (192u << 10));      // 160 KB
    int*   csrCur  = (int*)(ws + (384u << 10));      // 160 KB
    int*   flist   = (int*)(ws + (576u << 10));      // 160 KB
    int*   fcnt    = (int*)(ws + (768u << 10));      // 12 B
    float* sums    = (float*)(ws + (768u << 10) + 256);   // 256 B
    int*   partial = (int*)(ws + (768u << 10) + 4096);    // 157*4 B
    int*   pofs    = (int*)(ws + (768u << 10) + 8192);    // 157*4 B
    float* memA    = (float*)(ws + (1u << 20));      // 10.24 MB (always ws)
    float* memB;
    char*  csrBase;
    size_t csrBytes = (size_t)2 * nE * sizeof(uint2);
    size_t needBoth = (size_t)(1u << 20) + 2 * MEM_BYTES + csrBytes;
    if (ws_size >= needBoth) {
        memB = (float*)(ws + (1u << 20) + MEM_BYTES);
        csrBase = ws + (1u << 20) + 2 * MEM_BYTES;
    } else {
        memB = out + 1;  // fallback scratch; k_norm_tr overwrites it at the end
        csrBase = ws + (1u << 20) + MEM_BYTES;
    }
    uint2* csr = (uint2*)csrBase;

    const int EB = (nE + 255) / 256;

    // ---- CSR build (per call; workspace is re-poisoned between iterations) ----
    k_zero<<<SCAN_NBLK, 256, 0, stream>>>(deg, fcnt, sums);
    k_count<<<EB, 256, 0, stream>>>(eh, et, deg, nE);
    k_blocksum<<<SCAN_NBLK, 256, 0, stream>>>(deg, partial);
    k_scan_small<<<1, 256, 0, stream>>>(partial, pofs, offs);
    k_offsets<<<SCAN_NBLK, 256, 0, stream>>>(deg, pofs, offs, csrCur);
    k_scatter<<<EB, 256, 0, stream>>>(qh, qr, tt, eh, et, er, ev, csrCur, csr, nE);

    // ---- step 0: virtual one-hot source; nxt = memA ----
    k_init_decay<<<DEC_BLOCKS, 256, 0, stream>>>(qh, attn, memA, fcnt + 0, flist);
    k_fstep<true><<<16, 256, 0, stream>>>(csr, offs, flist, fcnt + 0, attn, 0,
                                          nullptr, qh, memA);
    // ---- steps 1,2: ping-pong memA <-> memB; final lands in memA ----
    float* curm = memA;
    float* nxtm = memB;
    for (int s = 1; s < BODY_LEN; ++s) {
        k_decay<<<DEC_BLOCKS, 256, 0, stream>>>(curm, nxtm, attn, s, fcnt + s, flist);
        k_fstep<false><<<1024, 256, 0, stream>>>(csr, offs, flist, fcnt + s, attn, s,
                                                 curm, nullptr, nxtm);
        float* tmp = curm; curm = nxtm; nxtm = tmp;
    }
    // curm == memA (final, ent-major, unnormalized)

    k_sums<<<128, 256, 0, stream>>>(curm, sums);
    k_norm_tr<<<N_ENT / 64 + 1, 256, 0, stream>>>(curm, sums, tt, out);
}